// Round 1
// baseline (338.509 us; speedup 1.0000x reference)
//
#include <hip/hip_runtime.h>
#include <stdint.h>

typedef short bf16x8 __attribute__((ext_vector_type(8)));
typedef float f32x4 __attribute__((ext_vector_type(4)));

__device__ __forceinline__ unsigned short f2bf(float f) {
  union { float f; unsigned int u; } v; v.f = f;
  unsigned int u = v.u;
  unsigned int r = (u + 0x7FFFu + ((u >> 16) & 1u)) >> 16;  // RNE
  return (unsigned short)r;
}

__device__ __forceinline__ void async16(const void* g, void* l) {
  __builtin_amdgcn_global_load_lds(
      (const __attribute__((address_space(1))) unsigned int*)g,
      (__attribute__((address_space(3))) unsigned int*)l, 16, 0, 0);
}

// ---------------- cast f32 -> bf16, 8 elems/thread ----------------
__global__ __launch_bounds__(256) void cast_f32_bf16(
    const float* __restrict__ in, unsigned short* __restrict__ out, int n8) {
  int i = blockIdx.x * 256 + threadIdx.x;
  if (i >= n8) return;
  const float4* p = (const float4*)in;
  float4 a = p[2 * (size_t)i], b = p[2 * (size_t)i + 1];
  union { bf16x8 v; unsigned short s[8]; } o;
  o.s[0] = f2bf(a.x); o.s[1] = f2bf(a.y); o.s[2] = f2bf(a.z); o.s[3] = f2bf(a.w);
  o.s[4] = f2bf(b.x); o.s[5] = f2bf(b.y); o.s[6] = f2bf(b.z); o.s[7] = f2bf(b.w);
  *(bf16x8*)(out + 8 * (size_t)i) = o.v;
}

// ---------------- C[m][n] = sum_k A[m][k]*B[n][k]  (both row-major, K-major) --
// OMODE: 0 = f32 out, 1 = f32 * (*scale_ptr), 2 = bf16 out
template <int OMODE>
__global__ __launch_bounds__(256) void gemm_bt(
    const unsigned short* __restrict__ A, const unsigned short* __restrict__ B,
    void* __restrict__ Cv, int M, int N, int K, const float* __restrict__ scale_ptr) {
  __shared__ unsigned short As[128 * 32];
  __shared__ unsigned short Bs[128 * 32];
  const int tid = threadIdx.x;
  const int w = tid >> 6, lane = tid & 63;
  const int m0 = blockIdx.y * 128, n0 = blockIdx.x * 128;
  const int wr = w >> 1, wc = w & 1;

  // staging: wave w covers tile rows [w*32, w*32+32), 16 rows per issue
  const int srow = lane >> 2;        // 0..15
  const int scol = (lane & 3) * 8;   // element offset within 32-wide K slab
  const int r0 = w * 32;
  const unsigned short* ga0 = A + (size_t)(m0 + r0 + srow) * K + scol;
  const unsigned short* ga1 = A + (size_t)(m0 + r0 + 16 + srow) * K + scol;
  const unsigned short* gb0 = B + (size_t)(n0 + r0 + srow) * K + scol;
  const unsigned short* gb1 = B + (size_t)(n0 + r0 + 16 + srow) * K + scol;
  unsigned short* la0 = &As[r0 * 32];
  unsigned short* la1 = &As[(r0 + 16) * 32];
  unsigned short* lb0 = &Bs[r0 * 32];
  unsigned short* lb1 = &Bs[(r0 + 16) * 32];

  // fragment read addresses (A-frag: row=lane&15, k=(lane>>4)*8; B symmetric)
  const int fr = lane & 15, koff = (lane >> 4) * 8;
  const unsigned short* pa[4];
  const unsigned short* pb[4];
#pragma unroll
  for (int i = 0; i < 4; ++i) {
    pa[i] = &As[(wr * 64 + i * 16 + fr) * 32 + koff];
    pb[i] = &Bs[(wc * 64 + i * 16 + fr) * 32 + koff];
  }

  f32x4 acc[4][4] = {};

  for (int k0 = 0; k0 < K; k0 += 32) {
    async16(ga0, la0); async16(ga1, la1);
    async16(gb0, lb0); async16(gb1, lb1);
    ga0 += 32; ga1 += 32; gb0 += 32; gb1 += 32;
    __syncthreads();  // drains vmcnt -> LDS tile complete
    bf16x8 af[4], bfg[4];
#pragma unroll
    for (int i = 0; i < 4; ++i) af[i] = *(const bf16x8*)pa[i];
#pragma unroll
    for (int j = 0; j < 4; ++j) bfg[j] = *(const bf16x8*)pb[j];
#pragma unroll
    for (int i = 0; i < 4; ++i) {
#pragma unroll
      for (int j = 0; j < 4; ++j) {
        acc[i][j] = __builtin_amdgcn_mfma_f32_16x16x32_bf16(af[i], bfg[j], acc[i][j], 0, 0, 0);
      }
    }
    __syncthreads();  // compute done before next stage overwrites
  }

  float sc = 1.0f;
  if (OMODE == 1) sc = *scale_ptr;
  // C/D layout: col = lane&15, row = (lane>>4)*4 + reg (m89/m91-verified)
  const int rr = m0 + wr * 64 + ((lane >> 4) << 2);
  const int cc = n0 + wc * 64 + (lane & 15);
#pragma unroll
  for (int i = 0; i < 4; ++i) {
#pragma unroll
    for (int j = 0; j < 4; ++j) {
#pragma unroll
      for (int t = 0; t < 4; ++t) {
        size_t idx = (size_t)(rr + i * 16 + t) * N + (cc + j * 16);
        if (OMODE == 2) ((unsigned short*)Cv)[idx] = f2bf(acc[i][j][t]);
        else            ((float*)Cv)[idx] = acc[i][j][t] * sc;
      }
    }
  }
}

// ---------------- power iteration step on 2048x2048 f32 matrix --------------
// t_out = Amat * (t_in / ||t_in||). Each block redundantly normalizes (det.),
// then computes 8 rows of the GEMV (32 threads/row). No atomics.
__global__ __launch_bounds__(256) void power_step(
    const float* __restrict__ Amat, const float* __restrict__ tin,
    float* __restrict__ tout) {
  __shared__ __align__(16) float vs[2048];
  __shared__ float wred[4];
  const int tid = threadIdx.x;
  float4 x0 = ((const float4*)tin)[2 * tid];
  float4 x1 = ((const float4*)tin)[2 * tid + 1];
  float ss = x0.x * x0.x + x0.y * x0.y + x0.z * x0.z + x0.w * x0.w +
             x1.x * x1.x + x1.y * x1.y + x1.z * x1.z + x1.w * x1.w;
#pragma unroll
  for (int o = 32; o > 0; o >>= 1) ss += __shfl_xor(ss, o);
  if ((tid & 63) == 0) wred[tid >> 6] = ss;
  __syncthreads();
  float inv = 1.0f / sqrtf(wred[0] + wred[1] + wred[2] + wred[3]);
  float4* vp = (float4*)vs;
  float4 y0 = {x0.x * inv, x0.y * inv, x0.z * inv, x0.w * inv};
  float4 y1 = {x1.x * inv, x1.y * inv, x1.z * inv, x1.w * inv};
  vp[2 * tid] = y0;
  vp[2 * tid + 1] = y1;
  __syncthreads();
  const int row = blockIdx.x * 8 + (tid >> 5);
  const int sub = tid & 31;
  const float4* Ar = (const float4*)(Amat + (size_t)row * 2048);
  float s = 0.f;
#pragma unroll 4
  for (int c = sub; c < 512; c += 32) {
    float4 a = Ar[c];
    float4 v = vp[c];
    s += a.x * v.x + a.y * v.y + a.z * v.z + a.w * v.w;
  }
#pragma unroll
  for (int o = 16; o > 0; o >>= 1) s += __shfl_xor(s, o);
  if (sub == 0) tout[row] = s;
}

__global__ void power_init(float* __restrict__ t0) {
  int i = blockIdx.x * 256 + threadIdx.x;
  unsigned int h = (unsigned int)i * 2654435761u;
  h ^= h >> 16; h *= 2246822519u; h ^= h >> 13;
  t0[i] = (float)(h & 0xFFFFu) * (1.0f / 65536.0f) - 0.5f;
}

// lambda(A4) = ||t_k|| (input was normalized); sigma = lambda^(1/8)
__global__ __launch_bounds__(256) void finalize_sigma(
    const float* __restrict__ tk, float* __restrict__ inv_scale) {
  __shared__ float wred[4];
  const int tid = threadIdx.x;
  float4 x0 = ((const float4*)tk)[2 * tid];
  float4 x1 = ((const float4*)tk)[2 * tid + 1];
  float ss = x0.x * x0.x + x0.y * x0.y + x0.z * x0.z + x0.w * x0.w +
             x1.x * x1.x + x1.y * x1.y + x1.z * x1.z + x1.w * x1.w;
#pragma unroll
  for (int o = 32; o > 0; o >>= 1) ss += __shfl_xor(ss, o);
  if ((tid & 63) == 0) wred[tid >> 6] = ss;
  __syncthreads();
  if (tid == 0) {
    float lam = sqrtf(wred[0] + wred[1] + wred[2] + wred[3]);  // sigma^8
    float sigma = exp2f(log2f(lam) * 0.125f);
    float scl = fmaxf(sigma, 1.0f);  // BOUND = 1.0
    inv_scale[0] = 1.0f / scl;
  }
}

extern "C" void kernel_launch(void* const* d_in, const int* in_sizes, int n_in,
                              void* d_out, int out_size, void* d_ws, size_t ws_size,
                              hipStream_t stream) {
  (void)in_sizes; (void)n_in; (void)out_size; (void)ws_size;
  const float* x = (const float*)d_in[0];   // [4*2048, 2048]
  const float* W = (const float*)d_in[1];   // [2048, 2048]
  float* out = (float*)d_out;
  char* ws = (char*)d_ws;
  const int K = 2048, N = 2048, M = 4 * 2048;

  unsigned short* xb  = (unsigned short*)(ws);                         // 32 MB
  unsigned short* Wb  = (unsigned short*)(ws + ((size_t)32 << 20));    //  8 MB
  unsigned short* Ab  = (unsigned short*)(ws + ((size_t)40 << 20));    //  8 MB
  unsigned short* A2b = (unsigned short*)(ws + ((size_t)48 << 20));    //  8 MB
  float* A4 = (float*)(ws + ((size_t)56 << 20));                       // 16 MB
  float* tv = (float*)(ws + ((size_t)72 << 20));                       // 2x2048 + scalar
  float* inv_scale = tv + 4096;

  cast_f32_bf16<<<(M * K / 8 + 255) / 256, 256, 0, stream>>>(x, xb, M * K / 8);
  cast_f32_bf16<<<(N * K / 8 + 255) / 256, 256, 0, stream>>>(W, Wb, N * K / 8);

  // squaring chain: A = Wb Wb^T (sigma^2), A2 = A^2 (sigma^4), A4 = A2^2 (sigma^8)
  gemm_bt<2><<<dim3(16, 16), 256, 0, stream>>>(Wb, Wb, Ab, 2048, 2048, 2048, nullptr);
  gemm_bt<2><<<dim3(16, 16), 256, 0, stream>>>(Ab, Ab, A2b, 2048, 2048, 2048, nullptr);
  gemm_bt<0><<<dim3(16, 16), 256, 0, stream>>>(A2b, A2b, A4, 2048, 2048, 2048, nullptr);

  power_init<<<8, 256, 0, stream>>>(tv);
  for (int s = 0; s < 20; ++s)
    power_step<<<256, 256, 0, stream>>>(A4, tv + (s & 1) * 2048, tv + ((s + 1) & 1) * 2048);
  finalize_sigma<<<1, 256, 0, stream>>>(tv, inv_scale);

  // out = (x @ W^T) * inv_scale
  gemm_bt<1><<<dim3(16, 64), 256, 0, stream>>>(xb, Wb, out, M, N, K, inv_scale);
}

// Round 2
// 285.133 us; speedup vs baseline: 1.1872x; 1.1872x over previous
//
#include <hip/hip_runtime.h>
#include <stdint.h>

typedef short bf16x8 __attribute__((ext_vector_type(8)));
typedef float f32x4 __attribute__((ext_vector_type(4)));

__device__ __forceinline__ unsigned short f2bf(float f) {
  union { float f; unsigned int u; } v; v.f = f;
  unsigned int u = v.u;
  return (unsigned short)((u + 0x7FFFu + ((u >> 16) & 1u)) >> 16);  // RNE
}
__device__ __forceinline__ float bf2f(unsigned short u) {
  union { unsigned int u; float f; } v; v.u = ((unsigned int)u) << 16;
  return v.f;
}
__device__ __forceinline__ void async16(const void* g, void* l) {
  __builtin_amdgcn_global_load_lds(
      (const __attribute__((address_space(1))) unsigned int*)g,
      (__attribute__((address_space(3))) unsigned int*)l, 16, 0, 0);
}

// ---------------- cast f32 -> bf16, 8 elems/thread ----------------
__global__ __launch_bounds__(256) void cast_f32_bf16(
    const float* __restrict__ in, unsigned short* __restrict__ out, int n8) {
  int i = blockIdx.x * 256 + threadIdx.x;
  if (i >= n8) return;
  const float4* p = (const float4*)in;
  float4 a = p[2 * (size_t)i], b = p[2 * (size_t)i + 1];
  union { bf16x8 v; unsigned short s[8]; } o;
  o.s[0] = f2bf(a.x); o.s[1] = f2bf(a.y); o.s[2] = f2bf(a.z); o.s[3] = f2bf(a.w);
  o.s[4] = f2bf(b.x); o.s[5] = f2bf(b.y); o.s[6] = f2bf(b.z); o.s[7] = f2bf(b.w);
  *(bf16x8*)(out + 8 * (size_t)i) = o.v;
}

// stage one 16KB chunk (128 rows x 64 cols bf16) into linear LDS.
// Source is pre-swizzled (16B chunk j of row r fetches global chunk j^(r&7))
// so swizzled reads see correct data (both-sides-or-neither rule).
__device__ __forceinline__ void stage16k(const unsigned short* __restrict__ g0,
                                         int ldK, unsigned short* lds, int tid) {
#pragma unroll
  for (int q = 0; q < 2; ++q) {
    int idx = q * 512 + tid;
    int r = idx >> 3;                 // 0..127
    int jj = (idx & 7) ^ (r & 7);     // swizzled 16B chunk
    async16(g0 + (size_t)r * ldK + jj * 8,
            lds + ((size_t)(q * 512 + (tid & ~63))) * 8);  // wave-uniform base
  }
}

// C[m][n] = sum_k A[m][k]*B[n][k]; BM=256 BN=128 BK=64, 512 thr (4Mx2N waves),
// 3-buffer LDS pipeline, counted vmcnt(6) per K-tile. Requires N==2048 here
// (grid decomposition bid&15), M%256==0, K%64==0, K/64>=3.
// OMODE: 1 = f32 * (*scale_ptr), 2 = bf16 out
template <int OMODE>
__global__ __launch_bounds__(512, 2) void gemm8p(
    const unsigned short* __restrict__ A, const unsigned short* __restrict__ B,
    void* __restrict__ Cv, int M, int N, int K, const float* __restrict__ scale_ptr) {
  __shared__ __align__(16) unsigned short AsBuf[3][256 * 64];  // 96 KB
  __shared__ __align__(16) unsigned short BsBuf[3][128 * 64];  // 48 KB
  const int tid = threadIdx.x;
  const int w = tid >> 6, lane = tid & 63;
  const int n0 = (blockIdx.x & 15) * 128;   // XCD x keeps n in {x, x+8}
  const int m0 = (blockIdx.x >> 4) * 256;
  const int wr = w >> 1, wc = w & 1;        // 4M x 2N wave grid
  const int NT = K >> 6;

  const unsigned short* Abase = A + (size_t)m0 * K;
  const unsigned short* Bbase = B + (size_t)n0 * K;

  unsigned short *a0 = AsBuf[0], *a1 = AsBuf[1], *a2 = AsBuf[2];
  unsigned short *b0 = BsBuf[0], *b1 = BsBuf[1], *b2 = BsBuf[2];

  // prologue: tiles 0,1 fully issued (12 loads); keep tile1's 6 in flight
  stage16k(Abase, K, a0, tid);
  stage16k(Abase + (size_t)128 * K, K, a0 + 128 * 64, tid);
  stage16k(Bbase, K, b0, tid);
  stage16k(Abase + 64, K, a1, tid);
  stage16k(Abase + (size_t)128 * K + 64, K, a1 + 128 * 64, tid);
  stage16k(Bbase + 64, K, b1, tid);
  asm volatile("s_waitcnt vmcnt(6)" ::: "memory");
  __builtin_amdgcn_s_barrier();
  asm volatile("" ::: "memory");

  const int fr = lane & 15;
  const int bc0 = (((lane >> 4) << 4)) ^ ((fr & 7) << 4);  // swizzled k-half 0
  const int bc1 = bc0 ^ 64;                                // k-half 1

  f32x4 acc[4][4] = {};

  for (int t = 0; t < NT; ++t) {
    const char* cA = (const char*)a0;
    const char* cB = (const char*)b0;
    const int ft = t + 2;
    const bool di = ft < NT;
#pragma unroll
    for (int i = 0; i < 2; ++i) {
      // ds reads for this phase: A mf={2i,2i+1} x kh, B nf=0..3 x kh
      bf16x8 af[2][2], bg[4][2];
#pragma unroll
      for (int m2 = 0; m2 < 2; ++m2) {
        int rb = (wr * 64 + (i * 2 + m2) * 16 + fr) * 128;
        af[m2][0] = *(const bf16x8*)(cA + rb + bc0);
        af[m2][1] = *(const bf16x8*)(cA + rb + bc1);
      }
#pragma unroll
      for (int nf = 0; nf < 4; ++nf) {
        int rb = (wc * 64 + nf * 16 + fr) * 128;
        bg[nf][0] = *(const bf16x8*)(cB + rb + bc0);
        bg[nf][1] = *(const bf16x8*)(cB + rb + bc1);
      }
      // prefetch tile t+2 into the buffer last read at tile t-1 (safe: barrier'd)
      if (di) {
        if (i == 0) {
          stage16k(Abase + (size_t)ft * 64, K, a2, tid);
          stage16k(Abase + (size_t)128 * K + (size_t)ft * 64, K, a2 + 128 * 64, tid);
        } else {
          stage16k(Bbase + (size_t)ft * 64, K, b2, tid);
        }
      }
      asm volatile("" ::: "memory");
      __builtin_amdgcn_s_barrier();
      asm volatile("" ::: "memory");
      __builtin_amdgcn_s_setprio(1);
#pragma unroll
      for (int m2 = 0; m2 < 2; ++m2)
#pragma unroll
        for (int nf = 0; nf < 4; ++nf)
#pragma unroll
          for (int kh = 0; kh < 2; ++kh)
            acc[i * 2 + m2][nf] = __builtin_amdgcn_mfma_f32_16x16x32_bf16(
                af[m2][kh], bg[nf][kh], acc[i * 2 + m2][nf], 0, 0, 0);
      __builtin_amdgcn_s_setprio(0);
      if (i == 0) {
        asm volatile("" ::: "memory");
        __builtin_amdgcn_s_barrier();
        asm volatile("" ::: "memory");
      }
    }
    // K-tile boundary: tile t+1's 6 loads must be done; keep tile t+2's 6 in flight
    if (t + 1 < NT) {
      if (t + 1 == NT - 1)
        asm volatile("s_waitcnt vmcnt(0) lgkmcnt(0)" ::: "memory");
      else
        asm volatile("s_waitcnt vmcnt(6) lgkmcnt(0)" ::: "memory");
      __builtin_amdgcn_s_barrier();
      asm volatile("" ::: "memory");
    }
    unsigned short* ta = a0; a0 = a1; a1 = a2; a2 = ta;
    unsigned short* tb = b0; b0 = b1; b1 = b2; b2 = tb;
  }

  float sc = 1.0f;
  if (OMODE == 1) sc = *scale_ptr;
  // C/D layout: col = lane&15, row = (lane>>4)*4 + reg (verified mapping)
  const int rr0 = m0 + wr * 64 + ((lane >> 4) << 2);
  const int cc0 = n0 + wc * 64 + fr;
#pragma unroll
  for (int mf = 0; mf < 4; ++mf)
#pragma unroll
    for (int nf = 0; nf < 4; ++nf)
#pragma unroll
      for (int tt = 0; tt < 4; ++tt) {
        size_t idx = (size_t)(rr0 + mf * 16 + tt) * N + (cc0 + nf * 16);
        if (OMODE == 2) ((unsigned short*)Cv)[idx] = f2bf(acc[mf][nf][tt]);
        else            ((float*)Cv)[idx] = acc[mf][nf][tt] * sc;
      }
}

// ---------------- power iteration step, bf16 matrix --------------
__global__ __launch_bounds__(256) void power_step_bf16(
    const unsigned short* __restrict__ Am, const float* __restrict__ tin,
    float* __restrict__ tout) {
  __shared__ __align__(16) float vs[2048];
  __shared__ float wred[4];
  const int tid = threadIdx.x;
  float4 x0 = ((const float4*)tin)[2 * tid];
  float4 x1 = ((const float4*)tin)[2 * tid + 1];
  float ss = x0.x * x0.x + x0.y * x0.y + x0.z * x0.z + x0.w * x0.w +
             x1.x * x1.x + x1.y * x1.y + x1.z * x1.z + x1.w * x1.w;
#pragma unroll
  for (int o = 32; o > 0; o >>= 1) ss += __shfl_xor(ss, o);
  if ((tid & 63) == 0) wred[tid >> 6] = ss;
  __syncthreads();
  float inv = 1.0f / sqrtf(wred[0] + wred[1] + wred[2] + wred[3]);
  float4* vp = (float4*)vs;
  float4 y0 = {x0.x * inv, x0.y * inv, x0.z * inv, x0.w * inv};
  float4 y1 = {x1.x * inv, x1.y * inv, x1.z * inv, x1.w * inv};
  vp[2 * tid] = y0;
  vp[2 * tid + 1] = y1;
  __syncthreads();
  const int row = blockIdx.x * 8 + (tid >> 5);
  const int sub = tid & 31;
  const bf16x8* Ar = (const bf16x8*)(Am + (size_t)row * 2048);
  float s = 0.f;
#pragma unroll 2
  for (int c = sub; c < 256; c += 32) {
    bf16x8 a = Ar[c];
    float4 v0 = vp[2 * c], v1 = vp[2 * c + 1];
    s += bf2f((unsigned short)a[0]) * v0.x + bf2f((unsigned short)a[1]) * v0.y +
         bf2f((unsigned short)a[2]) * v0.z + bf2f((unsigned short)a[3]) * v0.w +
         bf2f((unsigned short)a[4]) * v1.x + bf2f((unsigned short)a[5]) * v1.y +
         bf2f((unsigned short)a[6]) * v1.z + bf2f((unsigned short)a[7]) * v1.w;
  }
#pragma unroll
  for (int o = 16; o > 0; o >>= 1) s += __shfl_xor(s, o);
  if (sub == 0) tout[row] = s;
}

__global__ void power_init(float* __restrict__ t0) {
  int i = blockIdx.x * 256 + threadIdx.x;
  unsigned int h = (unsigned int)i * 2654435761u;
  h ^= h >> 16; h *= 2246822519u; h ^= h >> 13;
  t0[i] = (float)(h & 0xFFFFu) * (1.0f / 65536.0f) - 0.5f;
}

// lambda(A4) = ||t_k|| (input was normalized); sigma = lambda^(1/8)
__global__ __launch_bounds__(256) void finalize_sigma(
    const float* __restrict__ tk, float* __restrict__ inv_scale) {
  __shared__ float wred[4];
  const int tid = threadIdx.x;
  float4 x0 = ((const float4*)tk)[2 * tid];
  float4 x1 = ((const float4*)tk)[2 * tid + 1];
  float ss = x0.x * x0.x + x0.y * x0.y + x0.z * x0.z + x0.w * x0.w +
             x1.x * x1.x + x1.y * x1.y + x1.z * x1.z + x1.w * x1.w;
#pragma unroll
  for (int o = 32; o > 0; o >>= 1) ss += __shfl_xor(ss, o);
  if ((tid & 63) == 0) wred[tid >> 6] = ss;
  __syncthreads();
  if (tid == 0) {
    float lam = sqrtf(wred[0] + wred[1] + wred[2] + wred[3]);  // sigma^8
    float sigma = exp2f(log2f(lam) * 0.125f);
    float scl = fmaxf(sigma, 1.0f);  // BOUND = 1.0
    inv_scale[0] = 1.0f / scl;
  }
}

extern "C" void kernel_launch(void* const* d_in, const int* in_sizes, int n_in,
                              void* d_out, int out_size, void* d_ws, size_t ws_size,
                              hipStream_t stream) {
  (void)in_sizes; (void)n_in; (void)out_size; (void)ws_size;
  const float* x = (const float*)d_in[0];   // [8192, 2048]
  const float* W = (const float*)d_in[1];   // [2048, 2048]
  float* out = (float*)d_out;
  char* ws = (char*)d_ws;
  const int K = 2048, N = 2048, M = 4 * 2048;

  unsigned short* xb  = (unsigned short*)(ws);                        // 32 MB
  unsigned short* Wb  = (unsigned short*)(ws + ((size_t)32 << 20));   //  8 MB
  unsigned short* Am  = (unsigned short*)(ws + ((size_t)40 << 20));   //  8 MB
  unsigned short* A2m = (unsigned short*)(ws + ((size_t)48 << 20));   //  8 MB
  unsigned short* A4m = (unsigned short*)(ws + ((size_t)56 << 20));   //  8 MB
  float* tv = (float*)(ws + ((size_t)64 << 20));
  float* inv_scale = tv + 4096;

  cast_f32_bf16<<<(M * K / 8 + 255) / 256, 256, 0, stream>>>(x, xb, M * K / 8);
  cast_f32_bf16<<<(N * K / 8 + 255) / 256, 256, 0, stream>>>(W, Wb, N * K / 8);

  // squaring chain: A = W W^T (sigma^2), A2 = A A^T = A^2 (sigma^4), A4 (sigma^8)
  gemm8p<2><<<128, 512, 0, stream>>>(Wb, Wb, Am, 2048, 2048, 2048, nullptr);
  gemm8p<2><<<128, 512, 0, stream>>>(Am, Am, A2m, 2048, 2048, 2048, nullptr);
  gemm8p<2><<<128, 512, 0, stream>>>(A2m, A2m, A4m, 2048, 2048, 2048, nullptr);

  power_init<<<8, 256, 0, stream>>>(tv);
  for (int s = 0; s < 20; ++s)
    power_step_bf16<<<256, 256, 0, stream>>>(A4m, tv + (s & 1) * 2048,
                                             tv + ((s + 1) & 1) * 2048);
  finalize_sigma<<<1, 256, 0, stream>>>(tv, inv_scale);

  // out = (x @ W^T) * inv_scale
  gemm8p<1><<<512, 512, 0, stream>>>(xb, Wb, out, M, N, K, inv_scale);
}

// Round 3
// 237.387 us; speedup vs baseline: 1.4260x; 1.2011x over previous
//
#include <hip/hip_runtime.h>
#include <stdint.h>

typedef short bf16x8 __attribute__((ext_vector_type(8)));
typedef float f32x4 __attribute__((ext_vector_type(4)));

__device__ __forceinline__ unsigned short f2bf(float f) {
  union { float f; unsigned int u; } v; v.f = f;
  unsigned int u = v.u;
  return (unsigned short)((u + 0x7FFFu + ((u >> 16) & 1u)) >> 16);  // RNE
}
__device__ __forceinline__ float bf2f(unsigned short u) {
  union { unsigned int u; float f; } v; v.u = ((unsigned int)u) << 16;
  return v.f;
}
__device__ __forceinline__ void async16(const void* g, void* l) {
  __builtin_amdgcn_global_load_lds(
      (const __attribute__((address_space(1))) unsigned int*)g,
      (__attribute__((address_space(3))) unsigned int*)l, 16, 0, 0);
}

// ---------------- cast f32 -> bf16, 8 elems/thread ----------------
__global__ __launch_bounds__(256) void cast_f32_bf16(
    const float* __restrict__ in, unsigned short* __restrict__ out, int n8) {
  int i = blockIdx.x * 256 + threadIdx.x;
  if (i >= n8) return;
  const float4* p = (const float4*)in;
  float4 a = p[2 * (size_t)i], b = p[2 * (size_t)i + 1];
  union { bf16x8 v; unsigned short s[8]; } o;
  o.s[0] = f2bf(a.x); o.s[1] = f2bf(a.y); o.s[2] = f2bf(a.z); o.s[3] = f2bf(a.w);
  o.s[4] = f2bf(b.x); o.s[5] = f2bf(b.y); o.s[6] = f2bf(b.z); o.s[7] = f2bf(b.w);
  *(bf16x8*)(out + 8 * (size_t)i) = o.v;
}

// stage one 16KB chunk (128 rows x 64 cols bf16) into linear LDS, 512 threads.
// Source pre-swizzled (16B chunk j of row r fetches global chunk j^(r&7)):
// swizzled reads then see correct data (both-sides-or-neither).
__device__ __forceinline__ void stage16k(const unsigned short* __restrict__ g0,
                                         int ldK, unsigned short* lds, int tid) {
#pragma unroll
  for (int q = 0; q < 2; ++q) {
    int idx = q * 512 + tid;
    int r = idx >> 3;                 // 0..127
    int jj = (idx & 7) ^ (r & 7);     // swizzled 16B chunk
    async16(g0 + (size_t)r * ldK + jj * 8,
            lds + ((size_t)(q * 512 + (tid & ~63))) * 8);  // wave-uniform base
  }
}

// C[m][n] = sum_k A[m0+m][ks*K + k] * B[n0+n][ks*K + k], both row-major lda.
// BM=BN=256, BK=64, 512 thr = 8 waves (2M x 4N), per-wave 128x64 out.
// 2 K-tiles/iter, 8 phases, double-buffered LDS, counted vmcnt(4) at ph3/ph7.
// Requires K%128==0, K/128>=2, M%256==0, N%256==0.
// grid decode: n = bid%nTn, m = (bid/nTn)%mT, ks = bid/(nTn*mT).
// OMODE: 1 = f32 out * (*scale_ptr), 2 = bf16 out at plane ks (split-K partial)
template <int OMODE>
__global__ __launch_bounds__(512, 2) void gemm256(
    const unsigned short* __restrict__ A, const unsigned short* __restrict__ B,
    void* __restrict__ Cv, int M, int N, int lda, int K,
    int nTn, int mT, const float* __restrict__ scale_ptr) {
  __shared__ __align__(16) unsigned short As[2][256 * 64];  // 64 KB
  __shared__ __align__(16) unsigned short Bs[2][256 * 64];  // 64 KB
  const int tid = threadIdx.x;
  const int w = tid >> 6, lane = tid & 63;
  int bid = blockIdx.x;
  const int nb = bid % nTn; bid /= nTn;
  const int mb = bid % mT;  const int ks = bid / mT;
  const int m0 = mb * 256, n0 = nb * 256;
  const int wr = w >> 2, wc = w & 3;   // 2M x 4N waves
  const int R = K >> 7;                // iterations (pairs of K-tiles)

  const unsigned short* Ab = A + (size_t)m0 * lda + (size_t)ks * K;
  const unsigned short* Bb = B + (size_t)n0 * lda + (size_t)ks * K;

  // prologue slots: B0h0,B0h1,A0h0,A0h1,B1h0,B1h1 (12 loads/thread)
  stage16k(Bb,                          lda, &Bs[0][0],        tid);
  stage16k(Bb + (size_t)128 * lda,      lda, &Bs[0][128 * 64], tid);
  stage16k(Ab,                          lda, &As[0][0],        tid);
  stage16k(Ab + (size_t)128 * lda,      lda, &As[0][128 * 64], tid);
  stage16k(Bb + 64,                     lda, &Bs[1][0],        tid);
  stage16k(Bb + 64 + (size_t)128 * lda, lda, &Bs[1][128 * 64], tid);
  asm volatile("s_waitcnt vmcnt(4)" ::: "memory");  // tile0 landed, tile1.B in flight
  __builtin_amdgcn_s_barrier();
  asm volatile("" ::: "memory");

  const int fr = lane & 15;
  const int bc0 = ((lane >> 4) << 4) ^ ((fr & 7) << 4);  // swizzled k-half 0
  const int bc1 = bc0 ^ 64;                              // k-half 1

  f32x4 acc[8][4] = {};

  for (int r = 0; r < R; ++r) {
    const bool st = (r + 1 < R);  // stage pair r+1?
    bf16x8 bg[4][2];
#pragma unroll
    for (int ph = 0; ph < 8; ++ph) {
      const int d = ph >> 2, q = ph & 3;
      const char* cA = (const char*)&As[d][0];
      const char* cB = (const char*)&Bs[d][0];
      if (q == 0) {  // B-frags for this K-tile, register-resident 4 phases
#pragma unroll
        for (int nf = 0; nf < 4; ++nf) {
          int rb = (wc * 64 + nf * 16 + fr) * 128;
          bg[nf][0] = *(const bf16x8*)(cB + rb + bc0);
          bg[nf][1] = *(const bf16x8*)(cB + rb + bc1);
        }
      }
      bf16x8 af[2][2];
#pragma unroll
      for (int m2 = 0; m2 < 2; ++m2) {
        int rb = (wr * 128 + q * 32 + m2 * 16 + fr) * 128;
        af[m2][0] = *(const bf16x8*)(cA + rb + bc0);
        af[m2][1] = *(const bf16x8*)(cA + rb + bc1);
      }
      // stage slot schedule (targets proven read-retired at issue point):
      switch (ph) {
        case 0: stage16k(Ab + (size_t)(2 * r + 1) * 64, lda, &As[1][0], tid); break;
        case 1: stage16k(Ab + (size_t)(2 * r + 1) * 64 + (size_t)128 * lda, lda,
                         &As[1][128 * 64], tid); break;
        case 2: if (st) stage16k(Bb + (size_t)(2 * r + 2) * 64, lda, &Bs[0][0], tid); break;
        case 3: if (st) stage16k(Bb + (size_t)(2 * r + 2) * 64 + (size_t)128 * lda, lda,
                                 &Bs[0][128 * 64], tid); break;
        case 4: if (st) stage16k(Ab + (size_t)(2 * r + 2) * 64, lda, &As[0][0], tid); break;
        case 5: if (st) stage16k(Ab + (size_t)(2 * r + 2) * 64 + (size_t)128 * lda, lda,
                                 &As[0][128 * 64], tid); break;
        case 6: if (st) stage16k(Bb + (size_t)(2 * r + 3) * 64, lda, &Bs[1][0], tid); break;
        case 7: if (st) stage16k(Bb + (size_t)(2 * r + 3) * 64 + (size_t)128 * lda, lda,
                                 &Bs[1][128 * 64], tid); break;
      }
      asm volatile("" ::: "memory");
      __builtin_amdgcn_s_barrier();
      asm volatile("" ::: "memory");
      __builtin_amdgcn_s_setprio(1);
#pragma unroll
      for (int m2 = 0; m2 < 2; ++m2)
#pragma unroll
        for (int nf = 0; nf < 4; ++nf)
#pragma unroll
          for (int kh = 0; kh < 2; ++kh)
            acc[q * 2 + m2][nf] = __builtin_amdgcn_mfma_f32_16x16x32_bf16(
                af[m2][kh], bg[nf][kh], acc[q * 2 + m2][nf], 0, 0, 0);
      __builtin_amdgcn_s_setprio(0);
      asm volatile("" ::: "memory");
      if (ph == 3) {
        // next phase reads tile 2r+1 (B1: iter r-1 ph6/7; A1: ph0/1).
        if (st) asm volatile("s_waitcnt vmcnt(4)" ::: "memory");  // B0' stays in flight
        else    asm volatile("s_waitcnt vmcnt(0)" ::: "memory");
      } else if (ph == 7) {
        // next iter ph0 reads tile 2r+2 (B0': ph2/3; A0': ph4/5).
        if (st) asm volatile("s_waitcnt vmcnt(4)" ::: "memory");  // B1' stays in flight
      }
      __builtin_amdgcn_s_barrier();
      asm volatile("" ::: "memory");
    }
  }

  float sc = 1.0f;
  if (OMODE == 1) sc = *scale_ptr;
  size_t base = (OMODE == 2) ? (size_t)ks * ((size_t)M * N) : 0;
  // C/D layout: col = lane&15, row = (lane>>4)*4 + reg (verified)
  const int rr0 = m0 + wr * 128 + ((lane >> 4) << 2);
  const int cc0 = n0 + wc * 64 + fr;
#pragma unroll
  for (int mf = 0; mf < 8; ++mf)
#pragma unroll
    for (int nf = 0; nf < 4; ++nf)
#pragma unroll
      for (int tt = 0; tt < 4; ++tt) {
        size_t idx = base + (size_t)(rr0 + mf * 16 + tt) * N + (cc0 + nf * 16);
        if (OMODE == 2) ((unsigned short*)Cv)[idx] = f2bf(acc[mf][nf][tt]);
        else            ((float*)Cv)[idx] = acc[mf][nf][tt] * sc;
      }
}

// ---------------- sum np bf16 planes -> bf16 (in-place safe: out may be plane 0)
__global__ __launch_bounds__(256) void reduce_planes(
    const unsigned short* __restrict__ P, unsigned short* __restrict__ out,
    int n8, int np, size_t plane) {
  int i = blockIdx.x * 256 + threadIdx.x;
  if (i >= n8) return;
  float s[8] = {0.f, 0.f, 0.f, 0.f, 0.f, 0.f, 0.f, 0.f};
  for (int p = 0; p < np; ++p) {
    bf16x8 v = *(const bf16x8*)(P + (size_t)p * plane + (size_t)i * 8);
#pragma unroll
    for (int j = 0; j < 8; ++j) s[j] += bf2f((unsigned short)v[j]);
  }
  union { bf16x8 v; unsigned short u[8]; } o;
#pragma unroll
  for (int j = 0; j < 8; ++j) o.u[j] = f2bf(s[j]);
  *(bf16x8*)(out + (size_t)i * 8) = o.v;
}

// ---------------- power iteration step, bf16 matrix --------------
__global__ __launch_bounds__(256) void power_step_bf16(
    const unsigned short* __restrict__ Am, const float* __restrict__ tin,
    float* __restrict__ tout) {
  __shared__ __align__(16) float vs[2048];
  __shared__ float wred[4];
  const int tid = threadIdx.x;
  float4 x0 = ((const float4*)tin)[2 * tid];
  float4 x1 = ((const float4*)tin)[2 * tid + 1];
  float ss = x0.x * x0.x + x0.y * x0.y + x0.z * x0.z + x0.w * x0.w +
             x1.x * x1.x + x1.y * x1.y + x1.z * x1.z + x1.w * x1.w;
#pragma unroll
  for (int o = 32; o > 0; o >>= 1) ss += __shfl_xor(ss, o);
  if ((tid & 63) == 0) wred[tid >> 6] = ss;
  __syncthreads();
  float inv = 1.0f / sqrtf(wred[0] + wred[1] + wred[2] + wred[3]);
  float4* vp = (float4*)vs;
  float4 y0 = {x0.x * inv, x0.y * inv, x0.z * inv, x0.w * inv};
  float4 y1 = {x1.x * inv, x1.y * inv, x1.z * inv, x1.w * inv};
  vp[2 * tid] = y0;
  vp[2 * tid + 1] = y1;
  __syncthreads();
  const int row = blockIdx.x * 8 + (tid >> 5);
  const int sub = tid & 31;
  const bf16x8* Ar = (const bf16x8*)(Am + (size_t)row * 2048);
  float s = 0.f;
#pragma unroll 2
  for (int c = sub; c < 256; c += 32) {
    bf16x8 a = Ar[c];
    float4 v0 = vp[2 * c], v1 = vp[2 * c + 1];
    s += bf2f((unsigned short)a[0]) * v0.x + bf2f((unsigned short)a[1]) * v0.y +
         bf2f((unsigned short)a[2]) * v0.z + bf2f((unsigned short)a[3]) * v0.w +
         bf2f((unsigned short)a[4]) * v1.x + bf2f((unsigned short)a[5]) * v1.y +
         bf2f((unsigned short)a[6]) * v1.z + bf2f((unsigned short)a[7]) * v1.w;
  }
#pragma unroll
  for (int o = 16; o > 0; o >>= 1) s += __shfl_xor(s, o);
  if (sub == 0) tout[row] = s;
}

__global__ void power_init(float* __restrict__ t0) {
  int i = blockIdx.x * 256 + threadIdx.x;
  unsigned int h = (unsigned int)i * 2654435761u;
  h ^= h >> 16; h *= 2246822519u; h ^= h >> 13;
  t0[i] = (float)(h & 0xFFFFu) * (1.0f / 65536.0f) - 0.5f;
}

// lambda(A2) = ||t_k|| (input was normalized); sigma = lambda^(1/4)
__global__ __launch_bounds__(256) void finalize_sigma(
    const float* __restrict__ tk, float* __restrict__ inv_scale) {
  __shared__ float wred[4];
  const int tid = threadIdx.x;
  float4 x0 = ((const float4*)tk)[2 * tid];
  float4 x1 = ((const float4*)tk)[2 * tid + 1];
  float ss = x0.x * x0.x + x0.y * x0.y + x0.z * x0.z + x0.w * x0.w +
             x1.x * x1.x + x1.y * x1.y + x1.z * x1.z + x1.w * x1.w;
#pragma unroll
  for (int o = 32; o > 0; o >>= 1) ss += __shfl_xor(ss, o);
  if ((tid & 63) == 0) wred[tid >> 6] = ss;
  __syncthreads();
  if (tid == 0) {
    float lam = sqrtf(wred[0] + wred[1] + wred[2] + wred[3]);  // sigma^4
    float sigma = exp2f(log2f(lam) * 0.25f);
    float scl = fmaxf(sigma, 1.0f);  // BOUND = 1.0
    inv_scale[0] = 1.0f / scl;
  }
}

extern "C" void kernel_launch(void* const* d_in, const int* in_sizes, int n_in,
                              void* d_out, int out_size, void* d_ws, size_t ws_size,
                              hipStream_t stream) {
  (void)in_sizes; (void)n_in; (void)out_size; (void)ws_size;
  const float* x = (const float*)d_in[0];   // [8192, 2048]
  const float* W = (const float*)d_in[1];   // [2048, 2048]
  float* out = (float*)d_out;
  char* ws = (char*)d_ws;
  const int K = 2048, N = 2048, M = 4 * 2048;
  const size_t PLANE = (size_t)2048 * 2048;  // elems per bf16 plane (8 MB)

  unsigned short* xb = (unsigned short*)(ws);                       // 0-32 MB
  unsigned short* Wb = (unsigned short*)(ws + ((size_t)32 << 20));  // 32-40 MB
  unsigned short* P1 = (unsigned short*)(ws + ((size_t)40 << 20));  // 40-72 MB (4 planes)
  unsigned short* Am = P1;                                          // in-place reduce
  unsigned short* P2 = (unsigned short*)(ws + ((size_t)48 << 20));  // 48-64 MB (2 planes)
  unsigned short* A2m = P2;                                         // in-place reduce
  float* tv = (float*)(ws + ((size_t)72 << 20));
  float* inv_scale = tv + 4096;

  cast_f32_bf16<<<(M * K / 8 + 255) / 256, 256, 0, stream>>>(x, xb, M * K / 8);
  cast_f32_bf16<<<(N * K / 8 + 255) / 256, 256, 0, stream>>>(W, Wb, N * K / 8);

  // A = W W^T (sigma^2): split-K=4, grid 256
  gemm256<2><<<256, 512, 0, stream>>>(Wb, Wb, P1, 2048, 2048, 2048, 512, 8, 8, nullptr);
  reduce_planes<<<2048, 256, 0, stream>>>(P1, Am, (int)(PLANE / 8), 4, PLANE);
  // A2 = A A^T = A^2 (sigma^4): split-K=2, grid 128
  gemm256<2><<<128, 512, 0, stream>>>(Am, Am, P2, 2048, 2048, 2048, 1024, 8, 8, nullptr);
  reduce_planes<<<2048, 256, 0, stream>>>(P2, A2m, (int)(PLANE / 8), 2, PLANE);

  power_init<<<8, 256, 0, stream>>>(tv);
  for (int s = 0; s < 20; ++s)
    power_step_bf16<<<256, 256, 0, stream>>>(A2m, tv + (s & 1) * 2048,
                                             tv + ((s + 1) & 1) * 2048);
  finalize_sigma<<<1, 256, 0, stream>>>(tv, inv_scale);

  // out = (x @ W^T) * inv_scale : grid 256 (nTn=8 -> XCD-resident B panel)
  gemm256<1><<<256, 512, 0, stream>>>(xb, Wb, out, M, N, K, K, 8, 32, inv_scale);
}

// Round 4
// 227.939 us; speedup vs baseline: 1.4851x; 1.0415x over previous
//
#include <hip/hip_runtime.h>
#include <stdint.h>

typedef short bf16x8 __attribute__((ext_vector_type(8)));
typedef float f32x4 __attribute__((ext_vector_type(4)));

__device__ __forceinline__ unsigned short f2bf(float f) {
  union { float f; unsigned int u; } v; v.f = f;
  unsigned int u = v.u;
  return (unsigned short)((u + 0x7FFFu + ((u >> 16) & 1u)) >> 16);  // RNE
}
__device__ __forceinline__ float bf2f(unsigned short u) {
  union { unsigned int u; float f; } v; v.u = ((unsigned int)u) << 16;
  return v.f;
}
__device__ __forceinline__ void async16(const void* g, void* l) {
  __builtin_amdgcn_global_load_lds(
      (const __attribute__((address_space(1))) unsigned int*)g,
      (__attribute__((address_space(3))) unsigned int*)l, 16, 0, 0);
}

// ---------------- cast f32 -> bf16, 8 elems/thread ----------------
__global__ __launch_bounds__(256) void cast_f32_bf16(
    const float* __restrict__ in, unsigned short* __restrict__ out, int n8) {
  int i = blockIdx.x * 256 + threadIdx.x;
  if (i >= n8) return;
  const float4* p = (const float4*)in;
  float4 a = p[2 * (size_t)i], b = p[2 * (size_t)i + 1];
  union { bf16x8 v; unsigned short s[8]; } o;
  o.s[0] = f2bf(a.x); o.s[1] = f2bf(a.y); o.s[2] = f2bf(a.z); o.s[3] = f2bf(a.w);
  o.s[4] = f2bf(b.x); o.s[5] = f2bf(b.y); o.s[6] = f2bf(b.z); o.s[7] = f2bf(b.w);
  *(bf16x8*)(out + 8 * (size_t)i) = o.v;
}

// stage one 16KB chunk (128 rows x 64 cols bf16) into linear LDS, 512 threads.
// Source pre-swizzled (16B chunk j of row r fetches global chunk j^(r&7)):
// swizzled reads then see correct data (both-sides-or-neither).
__device__ __forceinline__ void stage16k(const unsigned short* __restrict__ g0,
                                         int ldK, unsigned short* lds, int tid) {
#pragma unroll
  for (int q = 0; q < 2; ++q) {
    int idx = q * 512 + tid;
    int r = idx >> 3;                 // 0..127
    int jj = (idx & 7) ^ (r & 7);     // swizzled 16B chunk
    async16(g0 + (size_t)r * ldK + jj * 8,
            lds + ((size_t)(q * 512 + (tid & ~63))) * 8);  // wave-uniform base
  }
}

// C[m][n] = sum_k A[m0+m][ks*K + k] * B[n0+n][ks*K + k], both row-major lda.
// BM=BN=256, BK=64, 512 thr = 8 waves (2M x 4N), per-wave 128x64 out.
// A triple-buffered, B double-buffered (160KB LDS); uniform schedule: every
// chunk staged >=5 phases before use; vmcnt(8) at ph3/ph7. K%128==0, K/128>=2.
// grid decode: mb = bid%mT (same-A blocks share an XCD), nb=(bid/mT)%nTn,
// ks = bid/(mT*nTn).
// OMODE: 1 = f32 out * (*scale_ptr), 2 = bf16 out at plane ks (split-K partial)
template <int OMODE>
__global__ __launch_bounds__(512, 2) void gemm256(
    const unsigned short* __restrict__ A, const unsigned short* __restrict__ B,
    void* __restrict__ Cv, int M, int N, int lda, int K,
    int nTn, int mT, const float* __restrict__ scale_ptr) {
  __shared__ __align__(16) unsigned short AsBuf[3][256 * 64];  // 96 KB
  __shared__ __align__(16) unsigned short BsBuf[2][256 * 64];  // 64 KB
  const int tid = threadIdx.x;
  const int w = tid >> 6, lane = tid & 63;
  int bid = blockIdx.x;
  const int mb = bid % mT; bid /= mT;
  const int nb = bid % nTn; const int ks = bid / nTn;
  const int m0 = mb * 256, n0 = nb * 256;
  const int wr = w >> 2, wc = w & 3;   // 2M x 4N waves
  const int R = K >> 7;                // iterations (pairs of K-tiles)

  const unsigned short* Ab = A + (size_t)m0 * lda + (size_t)ks * K;
  const unsigned short* Bb = B + (size_t)n0 * lda + (size_t)ks * K;

  unsigned short *a0 = AsBuf[0], *a1 = AsBuf[1], *a2 = AsBuf[2];
  unsigned short *b0 = BsBuf[0], *b1 = BsBuf[1];

  // prologue: A0,B0 then A1,B1 (16 loads/thread); vmcnt(8) -> A0,B0 landed
  stage16k(Ab,                          lda, a0,            tid);
  stage16k(Ab + (size_t)128 * lda,      lda, a0 + 128 * 64, tid);
  stage16k(Bb,                          lda, b0,            tid);
  stage16k(Bb + (size_t)128 * lda,      lda, b0 + 128 * 64, tid);
  stage16k(Ab + 64,                     lda, a1,            tid);
  stage16k(Ab + 64 + (size_t)128 * lda, lda, a1 + 128 * 64, tid);
  stage16k(Bb + 64,                     lda, b1,            tid);
  stage16k(Bb + 64 + (size_t)128 * lda, lda, b1 + 128 * 64, tid);
  asm volatile("s_waitcnt vmcnt(8)" ::: "memory");
  __builtin_amdgcn_s_barrier();
  asm volatile("" ::: "memory");

  const int fr = lane & 15;
  const int bc0 = ((lane >> 4) << 4) ^ ((fr & 7) << 4);  // swizzled k-half 0
  const int bc1 = bc0 ^ 64;                              // k-half 1

  f32x4 acc[8][4] = {};

  for (int r = 0; r < R; ++r) {
    const bool st = (r + 1 < R);  // stage tiles 2r+2, 2r+3?
    bf16x8 bg[4][2];
#pragma unroll
    for (int ph = 0; ph < 8; ++ph) {
      const int d = ph >> 2, q = ph & 3;
      const char* cA = (const char*)(d == 0 ? a0 : a1);
      const char* cB = (const char*)(d == 0 ? b0 : b1);
      if (q == 0) {  // B-frags for this K-tile, register-resident 4 phases
#pragma unroll
        for (int nf = 0; nf < 4; ++nf) {
          int rb = (wc * 64 + nf * 16 + fr) * 128;
          bg[nf][0] = *(const bf16x8*)(cB + rb + bc0);
          bg[nf][1] = *(const bf16x8*)(cB + rb + bc1);
        }
      }
      bf16x8 af[2][2];
#pragma unroll
      for (int m2 = 0; m2 < 2; ++m2) {
        int rb = (wr * 128 + q * 32 + m2 * 16 + fr) * 128;
        af[m2][0] = *(const bf16x8*)(cA + rb + bc0);
        af[m2][1] = *(const bf16x8*)(cA + rb + bc1);
      }
      // uniform stage schedule: all targets free (last read >=1 barrier ago),
      // all consumers >=5 phases ahead (covers HBM latency).
      if (st) switch (ph) {
        case 0: stage16k(Ab + (size_t)(2 * r + 2) * 64, lda, a2, tid); break;
        case 1: stage16k(Ab + (size_t)(2 * r + 2) * 64 + (size_t)128 * lda, lda,
                         a2 + 128 * 64, tid); break;
        case 2: stage16k(Bb + (size_t)(2 * r + 2) * 64, lda, b0, tid); break;
        case 3: stage16k(Bb + (size_t)(2 * r + 2) * 64 + (size_t)128 * lda, lda,
                         b0 + 128 * 64, tid); break;
        case 4: stage16k(Ab + (size_t)(2 * r + 3) * 64, lda, a0, tid); break;
        case 5: stage16k(Ab + (size_t)(2 * r + 3) * 64 + (size_t)128 * lda, lda,
                         a0 + 128 * 64, tid); break;
        case 6: stage16k(Bb + (size_t)(2 * r + 3) * 64, lda, b1, tid); break;
        case 7: stage16k(Bb + (size_t)(2 * r + 3) * 64 + (size_t)128 * lda, lda,
                         b1 + 128 * 64, tid); break;
      }
      asm volatile("" ::: "memory");
      __builtin_amdgcn_s_barrier();
      asm volatile("" ::: "memory");
      __builtin_amdgcn_s_setprio(1);
#pragma unroll
      for (int m2 = 0; m2 < 2; ++m2)
#pragma unroll
        for (int nf = 0; nf < 4; ++nf)
#pragma unroll
          for (int kh = 0; kh < 2; ++kh)
            acc[q * 2 + m2][nf] = __builtin_amdgcn_mfma_f32_16x16x32_bf16(
                af[m2][kh], bg[nf][kh], acc[q * 2 + m2][kh == 1 ? nf : nf], 0, 0, 0);
      __builtin_amdgcn_s_setprio(0);
      asm volatile("" ::: "memory");
      if (ph == 3) {
        // ph4 reads tiles staged last iter ph4-7 (8 loads = oldest outstanding)
        if (st) asm volatile("s_waitcnt vmcnt(8)" ::: "memory");
        else    asm volatile("s_waitcnt vmcnt(0)" ::: "memory");
      } else if (ph == 7) {
        // next iter ph0 reads tiles staged this iter ph0-3
        if (st) asm volatile("s_waitcnt vmcnt(8)" ::: "memory");
      }
      __builtin_amdgcn_s_barrier();
      asm volatile("" ::: "memory");
    }
    // A-buffer rotation: next iter low tile = a2, high = a0, stage target = a1
    unsigned short* t = a2; a2 = a1; a1 = a0; a0 = t;
  }

  float sc = 1.0f;
  if (OMODE == 1) sc = *scale_ptr;
  size_t base = (OMODE == 2) ? (size_t)ks * ((size_t)M * N) : 0;
  // C/D layout: col = lane&15, row = (lane>>4)*4 + reg (verified)
  const int rr0 = m0 + wr * 128 + ((lane >> 4) << 2);
  const int cc0 = n0 + wc * 64 + fr;
#pragma unroll
  for (int mf = 0; mf < 8; ++mf)
#pragma unroll
    for (int nf = 0; nf < 4; ++nf)
#pragma unroll
      for (int tt = 0; tt < 4; ++tt) {
        size_t idx = base + (size_t)(rr0 + mf * 16 + tt) * N + (cc0 + nf * 16);
        if (OMODE == 2) ((unsigned short*)Cv)[idx] = f2bf(acc[mf][nf][tt]);
        else            ((float*)Cv)[idx] = acc[mf][nf][tt] * sc;
      }
}

// ---------------- sum np bf16 planes -> bf16 (in-place safe: out may be plane 0)
__global__ __launch_bounds__(256) void reduce_planes(
    const unsigned short* __restrict__ P, unsigned short* __restrict__ out,
    int n8, int np, size_t plane) {
  int i = blockIdx.x * 256 + threadIdx.x;
  if (i >= n8) return;
  float s[8] = {0.f, 0.f, 0.f, 0.f, 0.f, 0.f, 0.f, 0.f};
  for (int p = 0; p < np; ++p) {
    bf16x8 v = *(const bf16x8*)(P + (size_t)p * plane + (size_t)i * 8);
#pragma unroll
    for (int j = 0; j < 8; ++j) s[j] += bf2f((unsigned short)v[j]);
  }
  union { bf16x8 v; unsigned short u[8]; } o;
#pragma unroll
  for (int j = 0; j < 8; ++j) o.u[j] = f2bf(s[j]);
  *(bf16x8*)(out + (size_t)i * 8) = o.v;
}

// ---------------- power iteration step, bf16 matrix --------------
__global__ __launch_bounds__(256) void power_step_bf16(
    const unsigned short* __restrict__ Am, const float* __restrict__ tin,
    float* __restrict__ tout) {
  __shared__ __align__(16) float vs[2048];
  __shared__ float wred[4];
  const int tid = threadIdx.x;
  float4 x0 = ((const float4*)tin)[2 * tid];
  float4 x1 = ((const float4*)tin)[2 * tid + 1];
  float ss = x0.x * x0.x + x0.y * x0.y + x0.z * x0.z + x0.w * x0.w +
             x1.x * x1.x + x1.y * x1.y + x1.z * x1.z + x1.w * x1.w;
#pragma unroll
  for (int o = 32; o > 0; o >>= 1) ss += __shfl_xor(ss, o);
  if ((tid & 63) == 0) wred[tid >> 6] = ss;
  __syncthreads();
  float inv = 1.0f / sqrtf(wred[0] + wred[1] + wred[2] + wred[3]);
  float4* vp = (float4*)vs;
  float4 y0 = {x0.x * inv, x0.y * inv, x0.z * inv, x0.w * inv};
  float4 y1 = {x1.x * inv, x1.y * inv, x1.z * inv, x1.w * inv};
  vp[2 * tid] = y0;
  vp[2 * tid + 1] = y1;
  __syncthreads();
  const int row = blockIdx.x * 8 + (tid >> 5);
  const int sub = tid & 31;
  const bf16x8* Ar = (const bf16x8*)(Am + (size_t)row * 2048);
  float s = 0.f;
#pragma unroll 2
  for (int c = sub; c < 256; c += 32) {
    bf16x8 a = Ar[c];
    float4 v0 = vp[2 * c], v1 = vp[2 * c + 1];
    s += bf2f((unsigned short)a[0]) * v0.x + bf2f((unsigned short)a[1]) * v0.y +
         bf2f((unsigned short)a[2]) * v0.z + bf2f((unsigned short)a[3]) * v0.w +
         bf2f((unsigned short)a[4]) * v1.x + bf2f((unsigned short)a[5]) * v1.y +
         bf2f((unsigned short)a[6]) * v1.z + bf2f((unsigned short)a[7]) * v1.w;
  }
#pragma unroll
  for (int o = 16; o > 0; o >>= 1) s += __shfl_xor(s, o);
  if (sub == 0) tout[row] = s;
}

__global__ void power_init(float* __restrict__ t0) {
  int i = blockIdx.x * 256 + threadIdx.x;
  unsigned int h = (unsigned int)i * 2654435761u;
  h ^= h >> 16; h *= 2246822519u; h ^= h >> 13;
  t0[i] = (float)(h & 0xFFFFu) * (1.0f / 65536.0f) - 0.5f;
}

// lambda(A2) = ||t_k|| (input was normalized); sigma = lambda^(1/4)
__global__ __launch_bounds__(256) void finalize_sigma(
    const float* __restrict__ tk, float* __restrict__ inv_scale) {
  __shared__ float wred[4];
  const int tid = threadIdx.x;
  float4 x0 = ((const float4*)tk)[2 * tid];
  float4 x1 = ((const float4*)tk)[2 * tid + 1];
  float ss = x0.x * x0.x + x0.y * x0.y + x0.z * x0.z + x0.w * x0.w +
             x1.x * x1.x + x1.y * x1.y + x1.z * x1.z + x1.w * x1.w;
#pragma unroll
  for (int o = 32; o > 0; o >>= 1) ss += __shfl_xor(ss, o);
  if ((tid & 63) == 0) wred[tid >> 6] = ss;
  __syncthreads();
  if (tid == 0) {
    float lam = sqrtf(wred[0] + wred[1] + wred[2] + wred[3]);  // sigma^4
    float sigma = exp2f(log2f(lam) * 0.25f);
    float scl = fmaxf(sigma, 1.0f);  // BOUND = 1.0
    inv_scale[0] = 1.0f / scl;
  }
}

extern "C" void kernel_launch(void* const* d_in, const int* in_sizes, int n_in,
                              void* d_out, int out_size, void* d_ws, size_t ws_size,
                              hipStream_t stream) {
  (void)in_sizes; (void)n_in; (void)out_size; (void)ws_size;
  const float* x = (const float*)d_in[0];   // [8192, 2048]
  const float* W = (const float*)d_in[1];   // [2048, 2048]
  float* out = (float*)d_out;
  char* ws = (char*)d_ws;
  const int K = 2048, N = 2048, M = 4 * 2048;
  const size_t PLANE = (size_t)2048 * 2048;  // elems per bf16 plane (8 MB)

  unsigned short* xb = (unsigned short*)(ws);                       // 0-32 MB
  unsigned short* Wb = (unsigned short*)(ws + ((size_t)32 << 20));  // 32-40 MB
  unsigned short* P1 = (unsigned short*)(ws + ((size_t)40 << 20));  // 40-72 MB (4 planes)
  unsigned short* Am = P1;                                          // in-place reduce
  unsigned short* P2 = (unsigned short*)(ws + ((size_t)48 << 20));  // 48-64 MB (2 planes)
  unsigned short* A2m = P2;                                         // in-place reduce
  float* tv = (float*)(ws + ((size_t)72 << 20));
  float* inv_scale = tv + 4096;

  cast_f32_bf16<<<(M * K / 8 + 255) / 256, 256, 0, stream>>>(x, xb, M * K / 8);
  cast_f32_bf16<<<(N * K / 8 + 255) / 256, 256, 0, stream>>>(W, Wb, N * K / 8);

  // A = W W^T (sigma^2): split-K=4, grid 256
  gemm256<2><<<256, 512, 0, stream>>>(Wb, Wb, P1, 2048, 2048, 2048, 512, 8, 8, nullptr);
  reduce_planes<<<2048, 256, 0, stream>>>(P1, Am, (int)(PLANE / 8), 4, PLANE);
  // A2 = A A^T = A^2 (sigma^4): split-K=2, grid 128
  gemm256<2><<<128, 512, 0, stream>>>(Am, Am, P2, 2048, 2048, 2048, 1024, 8, 8, nullptr);
  reduce_planes<<<2048, 256, 0, stream>>>(P2, A2m, (int)(PLANE / 8), 2, PLANE);

  power_init<<<8, 256, 0, stream>>>(tv);
  for (int s = 0; s < 20; ++s)
    power_step_bf16<<<256, 256, 0, stream>>>(A2m, tv + (s & 1) * 2048,
                                             tv + ((s + 1) & 1) * 2048);
  finalize_sigma<<<1, 256, 0, stream>>>(tv, inv_scale);

  // out = (x @ W^T) * inv_scale : grid 256, mT=32 (same-A blocks share an XCD)
  gemm256<1><<<256, 512, 0, stream>>>(xb, Wb, out, M, N, K, K, 8, 32, inv_scale);
}

// Round 5
// 198.180 us; speedup vs baseline: 1.7081x; 1.1502x over previous
//
#include <hip/hip_runtime.h>
#include <stdint.h>

typedef short bf16x8 __attribute__((ext_vector_type(8)));
typedef float f32x4 __attribute__((ext_vector_type(4)));

__device__ __forceinline__ unsigned short f2bf(float f) {
  union { float f; unsigned int u; } v; v.f = f;
  unsigned int u = v.u;
  return (unsigned short)((u + 0x7FFFu + ((u >> 16) & 1u)) >> 16);  // RNE
}
__device__ __forceinline__ float bf2f(unsigned short u) {
  union { unsigned int u; float f; } v; v.u = ((unsigned int)u) << 16;
  return v.f;
}
__device__ __forceinline__ void async16(const void* g, void* l) {
  __builtin_amdgcn_global_load_lds(
      (const __attribute__((address_space(1))) unsigned int*)g,
      (__attribute__((address_space(3))) unsigned int*)l, 16, 0, 0);
}

// ---------------- cast f32 -> bf16, 8 elems/thread ----------------
__global__ __launch_bounds__(256) void cast_f32_bf16(
    const float* __restrict__ in, unsigned short* __restrict__ out, int n8) {
  int i = blockIdx.x * 256 + threadIdx.x;
  if (i >= n8) return;
  const float4* p = (const float4*)in;
  float4 a = p[2 * (size_t)i], b = p[2 * (size_t)i + 1];
  union { bf16x8 v; unsigned short s[8]; } o;
  o.s[0] = f2bf(a.x); o.s[1] = f2bf(a.y); o.s[2] = f2bf(a.z); o.s[3] = f2bf(a.w);
  o.s[4] = f2bf(b.x); o.s[5] = f2bf(b.y); o.s[6] = f2bf(b.z); o.s[7] = f2bf(b.w);
  *(bf16x8*)(out + 8 * (size_t)i) = o.v;
}

// stage one 16KB chunk (128 rows x 64 cols bf16) into linear LDS, 512 threads.
// Source pre-swizzled (16B chunk j of row r fetches global chunk j^(r&7)):
// swizzled reads then see correct data (both-sides-or-neither).
__device__ __forceinline__ void stage16k(const unsigned short* __restrict__ g0,
                                         int ldK, unsigned short* lds, int tid) {
#pragma unroll
  for (int q = 0; q < 2; ++q) {
    int idx = q * 512 + tid;
    int r = idx >> 3;                 // 0..127
    int jj = (idx & 7) ^ (r & 7);     // swizzled 16B chunk
    async16(g0 + (size_t)r * ldK + jj * 8,
            lds + ((size_t)(q * 512 + (tid & ~63))) * 8);  // wave-uniform base
  }
}

// C[m][n] = sum_k A[m0+m][ks*K + k] * B[n0+n][ks*K + k], both row-major lda.
// BM=BN=256, BK=64, 512 thr = 8 waves (2M x 4N), per-wave 128x64 out.
// A triple-buffered, B double-buffered (160KB LDS); every chunk staged >=5
// phases before use; vmcnt(8) at ph3/ph7. K%128==0, K/128>=2.
// grid decode: mb = bid%mT (same-A blocks share an XCD), nb=(bid/mT)%nTn,
// ks = bid/(mT*nTn).
// OMODE: 1 = f32 out * (*scale_ptr), 2 = bf16 out at plane ks (split-K partial)
template <int OMODE>
__global__ __launch_bounds__(512, 2) void gemm256(
    const unsigned short* __restrict__ A, const unsigned short* __restrict__ B,
    void* __restrict__ Cv, int M, int N, int lda, int K,
    int nTn, int mT, const float* __restrict__ scale_ptr) {
  __shared__ __align__(16) unsigned short AsBuf[3][256 * 64];  // 96 KB
  __shared__ __align__(16) unsigned short BsBuf[2][256 * 64];  // 64 KB
  const int tid = threadIdx.x;
  const int w = tid >> 6, lane = tid & 63;
  int bid = blockIdx.x;
  const int mb = bid % mT; bid /= mT;
  const int nb = bid % nTn; const int ks = bid / nTn;
  const int m0 = mb * 256, n0 = nb * 256;
  const int wr = w >> 2, wc = w & 3;   // 2M x 4N waves
  const int R = K >> 7;                // iterations (pairs of K-tiles)

  const unsigned short* Ab = A + (size_t)m0 * lda + (size_t)ks * K;
  const unsigned short* Bb = B + (size_t)n0 * lda + (size_t)ks * K;

  unsigned short *a0 = AsBuf[0], *a1 = AsBuf[1], *a2 = AsBuf[2];
  unsigned short *b0 = BsBuf[0], *b1 = BsBuf[1];

  // prologue: A0,B0 then A1,B1 (16 loads/thread); vmcnt(8) -> A0,B0 landed
  stage16k(Ab,                          lda, a0,            tid);
  stage16k(Ab + (size_t)128 * lda,      lda, a0 + 128 * 64, tid);
  stage16k(Bb,                          lda, b0,            tid);
  stage16k(Bb + (size_t)128 * lda,      lda, b0 + 128 * 64, tid);
  stage16k(Ab + 64,                     lda, a1,            tid);
  stage16k(Ab + 64 + (size_t)128 * lda, lda, a1 + 128 * 64, tid);
  stage16k(Bb + 64,                     lda, b1,            tid);
  stage16k(Bb + 64 + (size_t)128 * lda, lda, b1 + 128 * 64, tid);
  asm volatile("s_waitcnt vmcnt(8)" ::: "memory");
  __builtin_amdgcn_s_barrier();
  asm volatile("" ::: "memory");

  const int fr = lane & 15;
  const int bc0 = ((lane >> 4) << 4) ^ ((fr & 7) << 4);  // swizzled k-half 0
  const int bc1 = bc0 ^ 64;                              // k-half 1

  f32x4 acc[8][4] = {};

  for (int r = 0; r < R; ++r) {
    const bool st = (r + 1 < R);  // stage tiles 2r+2, 2r+3?
    bf16x8 bg[4][2];
#pragma unroll
    for (int ph = 0; ph < 8; ++ph) {
      const int d = ph >> 2, q = ph & 3;
      const char* cA = (const char*)(d == 0 ? a0 : a1);
      const char* cB = (const char*)(d == 0 ? b0 : b1);
      if (q == 0) {  // B-frags for this K-tile, register-resident 4 phases
#pragma unroll
        for (int nf = 0; nf < 4; ++nf) {
          int rb = (wc * 64 + nf * 16 + fr) * 128;
          bg[nf][0] = *(const bf16x8*)(cB + rb + bc0);
          bg[nf][1] = *(const bf16x8*)(cB + rb + bc1);
        }
      }
      bf16x8 af[2][2];
#pragma unroll
      for (int m2 = 0; m2 < 2; ++m2) {
        int rb = (wr * 128 + q * 32 + m2 * 16 + fr) * 128;
        af[m2][0] = *(const bf16x8*)(cA + rb + bc0);
        af[m2][1] = *(const bf16x8*)(cA + rb + bc1);
      }
      // uniform stage schedule: all targets free (last read >=1 barrier ago),
      // all consumers >=5 phases ahead (covers HBM latency).
      if (st) switch (ph) {
        case 0: stage16k(Ab + (size_t)(2 * r + 2) * 64, lda, a2, tid); break;
        case 1: stage16k(Ab + (size_t)(2 * r + 2) * 64 + (size_t)128 * lda, lda,
                         a2 + 128 * 64, tid); break;
        case 2: stage16k(Bb + (size_t)(2 * r + 2) * 64, lda, b0, tid); break;
        case 3: stage16k(Bb + (size_t)(2 * r + 2) * 64 + (size_t)128 * lda, lda,
                         b0 + 128 * 64, tid); break;
        case 4: stage16k(Ab + (size_t)(2 * r + 3) * 64, lda, a0, tid); break;
        case 5: stage16k(Ab + (size_t)(2 * r + 3) * 64 + (size_t)128 * lda, lda,
                         a0 + 128 * 64, tid); break;
        case 6: stage16k(Bb + (size_t)(2 * r + 3) * 64, lda, b1, tid); break;
        case 7: stage16k(Bb + (size_t)(2 * r + 3) * 64 + (size_t)128 * lda, lda,
                         b1 + 128 * 64, tid); break;
      }
      asm volatile("" ::: "memory");
      __builtin_amdgcn_s_barrier();
      asm volatile("" ::: "memory");
      __builtin_amdgcn_s_setprio(1);
#pragma unroll
      for (int m2 = 0; m2 < 2; ++m2)
#pragma unroll
        for (int nf = 0; nf < 4; ++nf)
#pragma unroll
          for (int kh = 0; kh < 2; ++kh)
            acc[q * 2 + m2][nf] = __builtin_amdgcn_mfma_f32_16x16x32_bf16(
                af[m2][kh], bg[nf][kh], acc[q * 2 + m2][nf], 0, 0, 0);
      __builtin_amdgcn_s_setprio(0);
      asm volatile("" ::: "memory");
      if (ph == 3) {
        // ph4 reads tiles staged last iter ph4-7 (8 loads = oldest outstanding)
        if (st) asm volatile("s_waitcnt vmcnt(8)" ::: "memory");
        else    asm volatile("s_waitcnt vmcnt(0)" ::: "memory");
      } else if (ph == 7) {
        // next iter ph0 reads tiles staged this iter ph0-3
        if (st) asm volatile("s_waitcnt vmcnt(8)" ::: "memory");
      }
      __builtin_amdgcn_s_barrier();
      asm volatile("" ::: "memory");
    }
    // A-buffer rotation: next iter low tile = a2, high = a0, stage target = a1
    unsigned short* t = a2; a2 = a1; a1 = a0; a0 = t;
  }

  float sc = 1.0f;
  if (OMODE == 1) sc = *scale_ptr;
  size_t base = (OMODE == 2) ? (size_t)ks * ((size_t)M * N) : 0;
  // C/D layout: col = lane&15, row = (lane>>4)*4 + reg (verified)
  const int rr0 = m0 + wr * 128 + ((lane >> 4) << 2);
  const int cc0 = n0 + wc * 64 + fr;
#pragma unroll
  for (int mf = 0; mf < 8; ++mf)
#pragma unroll
    for (int nf = 0; nf < 4; ++nf)
#pragma unroll
      for (int tt = 0; tt < 4; ++tt) {
        size_t idx = base + (size_t)(rr0 + mf * 16 + tt) * N + (cc0 + nf * 16);
        if (OMODE == 2) ((unsigned short*)Cv)[idx] = f2bf(acc[mf][nf][tt]);
        else            ((float*)Cv)[idx] = acc[mf][nf][tt] * sc;
      }
}

// ---- sum np bf16 planes -> bf16 (in-place safe) + init power vec & shifts ----
__global__ __launch_bounds__(256) void reduce_planes_init(
    const unsigned short* __restrict__ P, unsigned short* __restrict__ out,
    int n8, int np, size_t plane, float* __restrict__ t0,
    float* __restrict__ czero) {
  int i = blockIdx.x * 256 + threadIdx.x;
  if (blockIdx.x < 8) {  // init 2048-elem start vector (deterministic hash)
    int j = blockIdx.x * 256 + threadIdx.x;
    unsigned int h = (unsigned int)j * 2654435761u;
    h ^= h >> 16; h *= 2246822519u; h ^= h >> 13;
    t0[j] = (float)(h & 0xFFFFu) * (1.0f / 65536.0f) - 0.5f;
    if (j == 0) czero[0] = 0.0f;
  }
  if (i >= n8) return;
  float s[8] = {0.f, 0.f, 0.f, 0.f, 0.f, 0.f, 0.f, 0.f};
  for (int p = 0; p < np; ++p) {
    bf16x8 v = *(const bf16x8*)(P + (size_t)p * plane + (size_t)i * 8);
#pragma unroll
    for (int j = 0; j < 8; ++j) s[j] += bf2f((unsigned short)v[j]);
  }
  union { bf16x8 v; unsigned short u[8]; } o;
#pragma unroll
  for (int j = 0; j < 8; ++j) o.u[j] = f2bf(s[j]);
  *(bf16x8*)(out + (size_t)i * 8) = o.v;
}

// ---------------- shifted power step: t_out = (A - c*I) * (t_in/||t_in||) ----
__global__ __launch_bounds__(256) void power_step_bf16(
    const unsigned short* __restrict__ Am, const float* __restrict__ tin,
    float* __restrict__ tout, const float* __restrict__ cptr) {
  __shared__ __align__(16) float vs[2048];
  __shared__ float wred[4];
  const int tid = threadIdx.x;
  float4 x0 = ((const float4*)tin)[2 * tid];
  float4 x1 = ((const float4*)tin)[2 * tid + 1];
  float ss = x0.x * x0.x + x0.y * x0.y + x0.z * x0.z + x0.w * x0.w +
             x1.x * x1.x + x1.y * x1.y + x1.z * x1.z + x1.w * x1.w;
#pragma unroll
  for (int o = 32; o > 0; o >>= 1) ss += __shfl_xor(ss, o);
  if ((tid & 63) == 0) wred[tid >> 6] = ss;
  __syncthreads();
  float inv = 1.0f / sqrtf(wred[0] + wred[1] + wred[2] + wred[3]);
  float4* vp = (float4*)vs;
  float4 y0 = {x0.x * inv, x0.y * inv, x0.z * inv, x0.w * inv};
  float4 y1 = {x1.x * inv, x1.y * inv, x1.z * inv, x1.w * inv};
  vp[2 * tid] = y0;
  vp[2 * tid + 1] = y1;
  __syncthreads();
  const int row = blockIdx.x * 8 + (tid >> 5);
  const int sub = tid & 31;
  const bf16x8* Ar = (const bf16x8*)(Am + (size_t)row * 2048);
  float s = 0.f;
#pragma unroll 2
  for (int c = sub; c < 256; c += 32) {
    bf16x8 a = Ar[c];
    float4 v0 = vp[2 * c], v1 = vp[2 * c + 1];
    s += bf2f((unsigned short)a[0]) * v0.x + bf2f((unsigned short)a[1]) * v0.y +
         bf2f((unsigned short)a[2]) * v0.z + bf2f((unsigned short)a[3]) * v0.w +
         bf2f((unsigned short)a[4]) * v1.x + bf2f((unsigned short)a[5]) * v1.y +
         bf2f((unsigned short)a[6]) * v1.z + bf2f((unsigned short)a[7]) * v1.w;
  }
#pragma unroll
  for (int o = 16; o > 0; o >>= 1) s += __shfl_xor(s, o);
  if (sub == 0) tout[row] = s - cptr[0] * vs[row];
}

// rough lambda estimate after unshifted steps: c = 0.49 * ||tk||
__global__ __launch_bounds__(256) void finalize_rough(
    const float* __restrict__ tk, float* __restrict__ cout) {
  __shared__ float wred[4];
  const int tid = threadIdx.x;
  float4 x0 = ((const float4*)tk)[2 * tid];
  float4 x1 = ((const float4*)tk)[2 * tid + 1];
  float ss = x0.x * x0.x + x0.y * x0.y + x0.z * x0.z + x0.w * x0.w +
             x1.x * x1.x + x1.y * x1.y + x1.z * x1.z + x1.w * x1.w;
#pragma unroll
  for (int o = 32; o > 0; o >>= 1) ss += __shfl_xor(ss, o);
  if ((tid & 63) == 0) wred[tid >> 6] = ss;
  __syncthreads();
  if (tid == 0)
    cout[0] = 0.49f * sqrtf(wred[0] + wred[1] + wred[2] + wred[3]);
}

// lambda1(A) ~= ||t_k|| + c  (input was normalized); sigma = sqrt(lambda)
__global__ __launch_bounds__(256) void finalize_sigma(
    const float* __restrict__ tk, const float* __restrict__ cptr,
    float* __restrict__ inv_scale) {
  __shared__ float wred[4];
  const int tid = threadIdx.x;
  float4 x0 = ((const float4*)tk)[2 * tid];
  float4 x1 = ((const float4*)tk)[2 * tid + 1];
  float ss = x0.x * x0.x + x0.y * x0.y + x0.z * x0.z + x0.w * x0.w +
             x1.x * x1.x + x1.y * x1.y + x1.z * x1.z + x1.w * x1.w;
#pragma unroll
  for (int o = 32; o > 0; o >>= 1) ss += __shfl_xor(ss, o);
  if ((tid & 63) == 0) wred[tid >> 6] = ss;
  __syncthreads();
  if (tid == 0) {
    float lam = sqrtf(wred[0] + wred[1] + wred[2] + wred[3]) + cptr[0];  // sigma^2
    float sigma = sqrtf(lam);
    float scl = fmaxf(sigma, 1.0f);  // BOUND = 1.0
    inv_scale[0] = 1.0f / scl;
  }
}

extern "C" void kernel_launch(void* const* d_in, const int* in_sizes, int n_in,
                              void* d_out, int out_size, void* d_ws, size_t ws_size,
                              hipStream_t stream) {
  (void)in_sizes; (void)n_in; (void)out_size; (void)ws_size;
  const float* x = (const float*)d_in[0];   // [8192, 2048]
  const float* W = (const float*)d_in[1];   // [2048, 2048]
  float* out = (float*)d_out;
  char* ws = (char*)d_ws;
  const int K = 2048, N = 2048, M = 4 * 2048;
  const size_t PLANE = (size_t)2048 * 2048;  // elems per bf16 plane (8 MB)

  unsigned short* xb = (unsigned short*)(ws);                       // 0-32 MB
  unsigned short* Wb = (unsigned short*)(ws + ((size_t)32 << 20));  // 32-40 MB
  unsigned short* P1 = (unsigned short*)(ws + ((size_t)40 << 20));  // 40-72 MB (4 planes)
  unsigned short* Am = P1;                                          // in-place reduce
  float* tv = (float*)(ws + ((size_t)72 << 20));
  float* inv_scale = tv + 4096;
  float* czero = tv + 4097;
  float* cshift = tv + 4098;

  cast_f32_bf16<<<(M * K / 8 + 255) / 256, 256, 0, stream>>>(x, xb, M * K / 8);
  cast_f32_bf16<<<(N * K / 8 + 255) / 256, 256, 0, stream>>>(W, Wb, N * K / 8);

  // A = W W^T (sigma^2): split-K=4, grid 256
  gemm256<2><<<256, 512, 0, stream>>>(Wb, Wb, P1, 2048, 2048, 2048, 512, 8, 8, nullptr);
  reduce_planes_init<<<2048, 256, 0, stream>>>(P1, Am, (int)(PLANE / 8), 4, PLANE,
                                               tv, czero);

  // shifted power iteration on A: 5 unshifted -> rough c -> 17 shifted
  int s = 0;
  for (; s < 5; ++s)
    power_step_bf16<<<256, 256, 0, stream>>>(Am, tv + (s & 1) * 2048,
                                             tv + ((s + 1) & 1) * 2048, czero);
  finalize_rough<<<1, 256, 0, stream>>>(tv + (s & 1) * 2048, cshift);
  for (; s < 22; ++s)
    power_step_bf16<<<256, 256, 0, stream>>>(Am, tv + (s & 1) * 2048,
                                             tv + ((s + 1) & 1) * 2048, cshift);
  finalize_sigma<<<1, 256, 0, stream>>>(tv + (s & 1) * 2048, cshift, inv_scale);

  // out = (x @ W^T) * inv_scale : grid 256, mT=32 (same-A blocks share an XCD)
  gemm256<1><<<256, 512, 0, stream>>>(xb, Wb, out, M, N, K, K, 8, 32, inv_scale);
}